// Round 6
// baseline (129.416 us; speedup 1.0000x reference)
//
#include <hip/hip_runtime.h>
#include <hip/hip_bf16.h>
#include <stdint.h>

#define UNITS 1024
#define IDIM  512
#define BATCH 2048
#define KTOT  1536   // UNITS + IDIM
#define NGATE 4096   // 4*UNITS
#define BK    64
#define NITER (KTOT / BK)   // 24

typedef short bf16x8 __attribute__((ext_vector_type(8)));   // 8 bf16 = 4 VGPRs
typedef float f32x4  __attribute__((ext_vector_type(4)));

#define AS3(p) ((__attribute__((address_space(3))) void*)(p))
#define AS1(p) ((const __attribute__((address_space(1))) void*)(p))

union P8 { bf16x8 v; __hip_bfloat16 e[8]; };

// ---------------------------------------------------------------------------
// prep: blocks [0,1536) cast-concat A = bf16(concat[h,x]); blocks [1536,4608)
// transpose W fp32 [1536][4096] -> Wt bf16 [4096][1536] (k-contiguous rows).
// ~50 MB HBM traffic => ~9-12 us, near its roofline.
// ---------------------------------------------------------------------------
#define NBLK_A 1536
#define NBLK_T 3072

__global__ __launch_bounds__(256) void prep(
    const float* __restrict__ x, const float* __restrict__ h,
    const float* __restrict__ W,
    __hip_bfloat16* __restrict__ A, __hip_bfloat16* __restrict__ Wt) {
  __shared__ float tile[32][65];
  const int tid = threadIdx.x;
  if (blockIdx.x < NBLK_A) {
    const int id = blockIdx.x * 256 + tid;
    const int r = id / (KTOT / 8);
    const int k = (id % (KTOT / 8)) * 8;
    const float* src = (k < UNITS) ? h + (size_t)r * UNITS + k
                                   : x + (size_t)r * IDIM + (k - UNITS);
    const float4 v0 = ((const float4*)src)[0];
    const float4 v1 = ((const float4*)src)[1];
    P8 o;
    o.e[0] = __float2bfloat16(v0.x); o.e[1] = __float2bfloat16(v0.y);
    o.e[2] = __float2bfloat16(v0.z); o.e[3] = __float2bfloat16(v0.w);
    o.e[4] = __float2bfloat16(v1.x); o.e[5] = __float2bfloat16(v1.y);
    o.e[6] = __float2bfloat16(v1.z); o.e[7] = __float2bfloat16(v1.w);
    *(bf16x8*)(A + (size_t)r * KTOT + k) = o.v;
  } else {
    const int b  = blockIdx.x - NBLK_A;   // 0..3071
    const int kb = b >> 7;                // 0..23
    const int nb = b & 127;               // 0..127
    const int k0 = kb * 64, n0 = nb * 32;
    const int n4 = (tid & 7) * 4;
    const int kk = tid >> 3;              // 0..31
#pragma unroll
    for (int rr = 0; rr < 64; rr += 32) {
      const float4 v = *(const float4*)(W + (size_t)(k0 + kk + rr) * NGATE + n0 + n4);
      tile[n4 + 0][kk + rr] = v.x; tile[n4 + 1][kk + rr] = v.y;
      tile[n4 + 2][kk + rr] = v.z; tile[n4 + 3][kk + rr] = v.w;
    }
    __syncthreads();
    const int n  = tid >> 3;
    const int k8 = (tid & 7) * 8;
    P8 o;
#pragma unroll
    for (int j = 0; j < 8; ++j) o.e[j] = __float2bfloat16(tile[n][k8 + j]);
    *(bf16x8*)(Wt + (size_t)(n0 + n) * KTOT + k0 + k8) = o.v;
  }
}

// ---------------------------------------------------------------------------
// GEMM + fused LSTM. Grid 1024 (3 blocks/CU resident -> 12 waves/CU, the m97
// occupancy that hides barrier drains; R4/R5 showed 2 blocks/CU stalls 2.3x
// over the LDS floor). Block tile: 64 rows x 32 units x 4 gates (128 vcols).
// 4 waves tile 2x2: wave = 32 rows x 64 vcols, acc[2][4] (32 VGPR).
// All 4 gates in-lane -> register-local LSTM epilogue.
//
// R4's proven single-barrier full-dbuf K-loop: per iter, FIRST issue
// global_load_lds prefetch of iter+1 (A->A[nxt], B->B[nxt]), then compute
// iter `it` (ds_read + MFMA absorb the prefetch latency), then ONE barrier
// whose vmcnt(0)+lgkm drain is covered by the other 2 resident blocks.
// (R5 lesson: pre-reading B to regs + extra barrier serializes; regressed.)
// LDS 48 KB: A0@0 A1@8K B0@16K B1@32K. 16B chunks XOR-swizzled
// chunk(row,k8)=row*8+(k8^(row&7)) -> 2 lanes/bank (free, m136; 0 conflicts
// measured R1-R5). XCD: bi%8 = ub%8 -> each XCD's 4 ub-slices = 1.57 MB of
// Wt stay L2-resident across their 32 mb-blocks.
// c_tm1 is pre-loaded into 8 VGPRs before the K-loop (hides epilogue HBM).
// ---------------------------------------------------------------------------
__global__ __launch_bounds__(256, 3) void lstm_gemm(
    const __hip_bfloat16* __restrict__ A,
    const __hip_bfloat16* __restrict__ Wt,
    const float* __restrict__ c_tm1,
    float* __restrict__ out) {
  __shared__ __attribute__((aligned(128))) char lds[49152];  // A0 A1 B0 B1

  const int tid  = threadIdx.x;
  const int w    = tid >> 6;     // wave 0..3 (uniform)
  const int lane = tid & 63;
  const int quad = lane >> 4;
  const int m16  = lane & 15;
  const int wr   = w >> 1;       // row half (0,1)
  const int wu   = w & 1;        // unit half (0,1)

  const int mb = blockIdx.x >> 5;   // 0..31
  const int ub = blockIdx.x & 31;   // 0..31  (XCD = bi%8 = ub%8)
  const int m0 = mb * 64;
  const int u0 = ub * 32;

  // A staging: 512 chunks (8 KB) / 256 thr = 2 per thread; B: 1024 -> 4.
  const __hip_bfloat16* aptr[2];
  const __hip_bfloat16* bptr[4];
  int adst[2], bdst[4];
#pragma unroll
  for (int s = 0; s < 2; ++s) {
    const int q   = s * 4 + w;            // 0..7
    const int ci  = q * 64 + lane;        // 0..511
    const int row = ci >> 3;              // 0..63
    const int k8  = (ci & 7) ^ (row & 7);
    aptr[s] = A + (size_t)(m0 + row) * KTOT + k8 * 8;
    adst[s] = q * 1024;
  }
#pragma unroll
  for (int s = 0; s < 4; ++s) {
    const int q   = s * 4 + w;            // 0..15
    const int ci  = q * 64 + lane;        // 0..1023
    const int row = ci >> 3;              // 0..127 (vcol)
    const int k8  = (ci & 7) ^ (row & 7);
    const int wrow = ((row >> 5) << 10) + u0 + (row & 31);
    bptr[s] = Wt + (size_t)wrow * KTOT + k8 * 8;
    bdst[s] = 16384 + q * 1024;
  }

  // pre-load this lane's 8 c_tm1 values (consumed only in the epilogue)
  const int u = u0 + wu * 16 + m16;
  float cpre[8];
#pragma unroll
  for (int i = 0; i < 2; ++i)
#pragma unroll
    for (int reg = 0; reg < 4; ++reg) {
      const int r = m0 + wr * 32 + i * 16 + quad * 4 + reg;
      cpre[i * 4 + reg] = c_tm1[(size_t)r * UNITS + u];
    }

  f32x4 acc[2][4];
#pragma unroll
  for (int i = 0; i < 2; ++i)
#pragma unroll
    for (int g = 0; g < 4; ++g) {
      f32x4 z = {0.f, 0.f, 0.f, 0.f};
      acc[i][g] = z;
    }

  // prologue: stage iter 0 into buffer 0
#pragma unroll
  for (int s = 0; s < 2; ++s)
    __builtin_amdgcn_global_load_lds(AS1(aptr[s]), AS3(lds + adst[s]), 16, 0, 0);
#pragma unroll
  for (int s = 0; s < 4; ++s)
    __builtin_amdgcn_global_load_lds(AS1(bptr[s]), AS3(lds + bdst[s]), 16, 0, 0);
  __syncthreads();

  for (int it = 0; it < NITER; ++it) {
    const int cur = it & 1;
    const int nxt = cur ^ 1;
    // prefetch iter it+1 into buffers `nxt` (issued BEFORE compute)
    if (it < NITER - 1) {
      const int koff = (it + 1) * BK;
#pragma unroll
      for (int s = 0; s < 2; ++s)
        __builtin_amdgcn_global_load_lds(AS1(aptr[s] + koff),
                                         AS3(lds + adst[s] + nxt * 8192), 16, 0, 0);
#pragma unroll
      for (int s = 0; s < 4; ++s)
        __builtin_amdgcn_global_load_lds(AS1(bptr[s] + koff),
                                         AS3(lds + bdst[s] + nxt * 16384), 16, 0, 0);
    }
    // compute iter `it` from buffers `cur`
    const char* abuf = lds + cur * 8192;
    const char* bbuf = lds + 16384 + cur * 16384;
#pragma unroll
    for (int t = 0; t < 2; ++t) {
      bf16x8 a[2], b[4];
#pragma unroll
      for (int i = 0; i < 2; ++i) {
        const int row  = wr * 32 + i * 16 + m16;
        const int slot = (t * 4 + quad) ^ (row & 7);
        a[i] = *(const bf16x8*)(abuf + (row * 8 + slot) * 16);
      }
#pragma unroll
      for (int g = 0; g < 4; ++g) {
        const int vr   = g * 32 + wu * 16 + m16;
        const int slot = (t * 4 + quad) ^ (vr & 7);
        b[g] = *(const bf16x8*)(bbuf + (vr * 8 + slot) * 16);
      }
#pragma unroll
      for (int g = 0; g < 4; ++g)
#pragma unroll
        for (int i = 0; i < 2; ++i)
          acc[i][g] = __builtin_amdgcn_mfma_f32_16x16x32_bf16(a[i], b[g], acc[i][g], 0, 0, 0);
    }
    __syncthreads();   // single barrier: drains prefetch + fences `cur` reads
  }

  // fused LSTM epilogue -- all 4 gates in-lane
#pragma unroll
  for (int i = 0; i < 2; ++i)
#pragma unroll
    for (int reg = 0; reg < 4; ++reg) {
      const int r = m0 + wr * 32 + i * 16 + quad * 4 + reg;
      const float z0 = acc[i][0][reg];   // gate i
      const float z1 = acc[i][1][reg];   // gate f
      const float z2 = acc[i][2][reg];   // c_tilde
      const float z3 = acc[i][3][reg];   // gate o
      const float ig = 1.f / (1.f + __expf(-z0));
      const float fg = 1.f / (1.f + __expf(-z1));
      const float ct = 1.f - 2.f / (__expf(2.f * z2) + 1.f);   // tanh, inf-safe
      const float og = 1.f / (1.f + __expf(-z3));
      const float cc = fg * cpre[i * 4 + reg] + ig * ct;
      const float hh = og * (1.f - 2.f / (__expf(2.f * cc) + 1.f));
      out[(size_t)r * UNITS + u] = hh;
      out[(size_t)BATCH * UNITS + (size_t)r * UNITS + u] = cc;
    }
}

// ---------------------------------------------------------------------------
// Fallback (only if d_ws too small): naive fp32, correct but slow.
// ---------------------------------------------------------------------------
__global__ __launch_bounds__(256) void lstm_naive(
    const float* __restrict__ x, const float* __restrict__ h,
    const float* __restrict__ c_tm1, const float* __restrict__ W,
    float* __restrict__ out) {
  int idx = blockIdx.x * 256 + threadIdx.x;
  int r = idx / UNITS;
  int u = idx % UNITS;
  float z[4] = {0.f, 0.f, 0.f, 0.f};
  for (int k = 0; k < KTOT; ++k) {
    float a = (k < UNITS) ? h[(size_t)r * UNITS + k] : x[(size_t)r * IDIM + k - UNITS];
#pragma unroll
    for (int g = 0; g < 4; ++g)
      z[g] += a * W[(size_t)k * NGATE + g * UNITS + u];
  }
  float ig = 1.f / (1.f + __expf(-z[0]));
  float fg = 1.f / (1.f + __expf(-z[1]));
  float ct = 1.f - 2.f / (__expf(2.f * z[2]) + 1.f);
  float og = 1.f / (1.f + __expf(-z[3]));
  float cc = fg * c_tm1[(size_t)r * UNITS + u] + ig * ct;
  float hh = og * (1.f - 2.f / (__expf(2.f * cc) + 1.f));
  out[(size_t)r * UNITS + u] = hh;
  out[(size_t)BATCH * UNITS + (size_t)r * UNITS + u] = cc;
}

extern "C" void kernel_launch(void* const* d_in, const int* in_sizes, int n_in,
                              void* d_out, int out_size, void* d_ws, size_t ws_size,
                              hipStream_t stream) {
  const float* x = (const float*)d_in[0];   // [2048][512]
  const float* h = (const float*)d_in[1];   // [2048][1024]
  const float* c = (const float*)d_in[2];   // [2048][1024]
  const float* W = (const float*)d_in[3];   // [1536][4096]
  float* out = (float*)d_out;               // h then c, 2 x [2048][1024]

  const size_t needA  = (size_t)BATCH * KTOT * sizeof(__hip_bfloat16);  // 6.29 MB
  const size_t needWt = (size_t)NGATE * KTOT * sizeof(__hip_bfloat16);  // 12.58 MB
  if (ws_size < needA + needWt) {
    hipLaunchKernelGGL(lstm_naive, dim3((BATCH * UNITS) / 256), dim3(256), 0, stream,
                       x, h, c, W, out);
    return;
  }

  __hip_bfloat16* A  = (__hip_bfloat16*)d_ws;
  __hip_bfloat16* Wt = (__hip_bfloat16*)((char*)d_ws + needA);

  hipLaunchKernelGGL(prep, dim3(NBLK_A + NBLK_T), dim3(256), 0, stream, x, h, W, A, Wt);
  hipLaunchKernelGGL(lstm_gemm, dim3(1024), dim3(256), 0, stream, A, Wt, c, out);
}

// Round 7
// 124.701 us; speedup vs baseline: 1.0378x; 1.0378x over previous
//
#include <hip/hip_runtime.h>
#include <hip/hip_bf16.h>
#include <stdint.h>

#define UNITS 1024
#define IDIM  512
#define BATCH 2048
#define KTOT  1536   // UNITS + IDIM
#define NGATE 4096   // 4*UNITS
#define NKK   48     // KTOT / 32 k-chunks
#define NITER 24     // K-loop iters (BK=64 = 2 kk per iter)

typedef short bf16x8 __attribute__((ext_vector_type(8)));   // 8 bf16 = 4 VGPRs
typedef float f32x4  __attribute__((ext_vector_type(4)));

union P8 { bf16x8 v; __hip_bfloat16 e[8]; };

// Fragment-ordered layouts (the whole point of R7):
//   A2: frag(ii,kk) at [(ii*NKK + kk)*64 + L] * 16B ; lane L holds
//       A[ii*16 + (L&15)][kk*32 + (L>>4)*8 .. +8]   (ii = row/16, 128 total)
//   Wt2: frag(jj,kk) likewise; lane L holds W^T[jj*16 + (L&15)][k...] where
//       jj = physical gate-row/16 (256 total).
// A GEMM fragment load is then ONE global_load_dwordx4 per lane, fully
// coalesced (64 lanes x 16B = 1KB contiguous). No LDS. No barriers.

// ---------------------------------------------------------------------------
// prep: blocks [0,1536): A2 fragments from concat[h,x] (each block emits 4KB,
// dest perfectly contiguous per wave). Blocks [1536,4608): W fp32 -> Wt2 bf16
// fragments via LDS 64k x 32n tile (pad 65 -> 2-way banks, free).
// ---------------------------------------------------------------------------
#define NBLK_A 1536
#define NBLK_T 3072

__global__ __launch_bounds__(256) void prep(
    const float* __restrict__ x, const float* __restrict__ h,
    const float* __restrict__ W,
    bf16x8* __restrict__ A2, bf16x8* __restrict__ Wt2) {
  __shared__ float tile[32][65];
  const int tid = threadIdx.x;
  if (blockIdx.x < NBLK_A) {
    const int gid = blockIdx.x * 256 + tid;   // one 16B fragment-slice each
    const int f  = gid >> 6;                  // fragment 0..6143 (128 ii x 48 kk)
    const int L  = gid & 63;
    const int ii = f / NKK;
    const int kk = f - ii * NKK;
    const int r  = ii * 16 + (L & 15);
    const int k  = kk * 32 + (L >> 4) * 8;
    const float* src = (k < UNITS) ? h + (size_t)r * UNITS + k
                                   : x + (size_t)r * IDIM + (k - UNITS);
    const float4 v0 = ((const float4*)src)[0];
    const float4 v1 = ((const float4*)src)[1];
    P8 o;
    o.e[0] = __float2bfloat16(v0.x); o.e[1] = __float2bfloat16(v0.y);
    o.e[2] = __float2bfloat16(v0.z); o.e[3] = __float2bfloat16(v0.w);
    o.e[4] = __float2bfloat16(v1.x); o.e[5] = __float2bfloat16(v1.y);
    o.e[6] = __float2bfloat16(v1.z); o.e[7] = __float2bfloat16(v1.w);
    A2[gid] = o.v;                            // contiguous 1KB per wave
  } else {
    const int b  = blockIdx.x - NBLK_A;   // 0..3071
    const int kb = b >> 7;                // 0..23
    const int nb = b & 127;               // 0..127
    const int k0 = kb * 64, n0 = nb * 32;
    // phase 1: coalesced float4 reads of W rows -> LDS transposed
    const int n4 = (tid & 7) * 4;
    const int kk = tid >> 3;              // 0..31
#pragma unroll
    for (int rr = 0; rr < 64; rr += 32) {
      const float4 v = *(const float4*)(W + (size_t)(k0 + kk + rr) * NGATE + n0 + n4);
      tile[n4 + 0][kk + rr] = v.x; tile[n4 + 1][kk + rr] = v.y;
      tile[n4 + 2][kk + rr] = v.z; tile[n4 + 3][kk + rr] = v.w;
    }
    __syncthreads();
    // phase 2: emit 4 fragments (2 jj x 2 kk), dest contiguous per wave
    const int L    = tid & 63;
    const int half = tid >> 6;            // 0..3
    const int jl   = half >> 1;           // jj local
    const int kl   = half & 1;            // kk local
    const int nloc = (L & 15) + jl * 16;  // 0..31
    const int kloc = kl * 32 + (L >> 4) * 8;   // 0..63 (2-way LDS banks: free)
    P8 o;
#pragma unroll
    for (int j = 0; j < 8; ++j) o.e[j] = __float2bfloat16(tile[nloc][kloc + j]);
    const int jj = (n0 >> 4) + jl;        // 0..255
    const int kc = (k0 >> 5) + kl;        // 0..47
    Wt2[(size_t)(jj * NKK + kc) * 64 + L] = o.v;
  }
}

// ---------------------------------------------------------------------------
// GEMM + fused LSTM -- NO LDS, NO BARRIERS. Grid 512; block 4 waves tiling
// 2x2 over 128 rows x 32 units x 4 gates; wave = 64 rows x 64 vcols,
// acc[4][4] (64 VGPR). Fragments double-buffered in VGPRs; per iter: 16
// coalesced dwordx4 loads (next iter) + 32 MFMA (current). The compiler
// pipelines VGPR-dest loads with partial vmcnt waits -- the thing the
// barrier'd LDS structure could not do (R4-R6 all stall-bound ~2000cyc/iter
// vs ~500 of work). L2 roofline: ~32KB/block-iter -> ~400MB total @34.5TB/s
// ~= 12us, balanced against the 12.4us MFMA floor.
// XCD: bi%8 = ub%8 -> each XCD's B slice = 1.5MB L2-resident; all 16 mb
// groups co-resident -> A kk-slices L2-shared per iter.
// ---------------------------------------------------------------------------
__global__ __launch_bounds__(256, 2) void lstm_gemm(
    const bf16x8* __restrict__ A2,
    const bf16x8* __restrict__ Wt2,
    const float* __restrict__ c_tm1,
    float* __restrict__ out) {
  const int tid  = threadIdx.x;
  const int w    = tid >> 6;     // wave 0..3 (uniform)
  const int lane = tid & 63;
  const int quad = lane >> 4;
  const int m16  = lane & 15;
  const int wr   = w >> 1;       // row half (0,1)
  const int wu   = w & 1;        // unit half (0,1)

  const int mb = blockIdx.x >> 5;   // 0..15
  const int ub = blockIdx.x & 31;   // 0..31  (XCD = bi%8 = ub%8)
  const int m0 = mb * 128;
  const int u0 = ub * 32;

  // fragment base offsets (in 16B units); step per kk = 64
  size_t aoff[4], boff[4];
  const int ii0 = mb * 8 + wr * 4;
#pragma unroll
  for (int i = 0; i < 4; ++i)
    aoff[i] = (size_t)((ii0 + i) * NKK) * 64 + lane;
#pragma unroll
  for (int g = 0; g < 4; ++g) {
    const int jj = g * 64 + ub * 2 + wu;   // physical row /16 of gate g block
    boff[g] = (size_t)(jj * NKK) * 64 + lane;
  }

  f32x4 acc[4][4];
#pragma unroll
  for (int i = 0; i < 4; ++i)
#pragma unroll
    for (int g = 0; g < 4; ++g) {
      f32x4 z = {0.f, 0.f, 0.f, 0.f};
      acc[i][g] = z;
    }

  bf16x8 a[2][4][2], b[2][4][2];   // [buf][i|g][t]

  // prologue: load iter 0 (kk = 0,1)
#pragma unroll
  for (int t = 0; t < 2; ++t) {
#pragma unroll
    for (int i = 0; i < 4; ++i) a[0][i][t] = A2[aoff[i] + t * 64];
#pragma unroll
    for (int g = 0; g < 4; ++g) b[0][g][t] = Wt2[boff[g] + t * 64];
  }

#pragma unroll 2
  for (int it = 0; it < NITER; ++it) {
    const int cur = it & 1;
    const int nxt = cur ^ 1;
    if (it < NITER - 1) {
      const int kk = (it + 1) * 2;
#pragma unroll
      for (int t = 0; t < 2; ++t) {
#pragma unroll
        for (int i = 0; i < 4; ++i) a[nxt][i][t] = A2[aoff[i] + (kk + t) * 64];
#pragma unroll
        for (int g = 0; g < 4; ++g) b[nxt][g][t] = Wt2[boff[g] + (kk + t) * 64];
      }
    }
#pragma unroll
    for (int t = 0; t < 2; ++t)
#pragma unroll
      for (int g = 0; g < 4; ++g)
#pragma unroll
        for (int i = 0; i < 4; ++i)
          acc[i][g] = __builtin_amdgcn_mfma_f32_16x16x32_bf16(a[cur][i][t],
                                                              b[cur][g][t],
                                                              acc[i][g], 0, 0, 0);
  }

  // fused LSTM epilogue -- all 4 gates in-lane
  const int u = u0 + wu * 16 + m16;
#pragma unroll
  for (int i = 0; i < 4; ++i)
#pragma unroll
    for (int reg = 0; reg < 4; ++reg) {
      const int r = m0 + wr * 64 + i * 16 + quad * 4 + reg;
      const float z0 = acc[i][0][reg];   // gate i
      const float z1 = acc[i][1][reg];   // gate f
      const float z2 = acc[i][2][reg];   // c_tilde
      const float z3 = acc[i][3][reg];   // gate o
      const float ig = 1.f / (1.f + __expf(-z0));
      const float fg = 1.f / (1.f + __expf(-z1));
      const float ct = 1.f - 2.f / (__expf(2.f * z2) + 1.f);   // tanh, inf-safe
      const float og = 1.f / (1.f + __expf(-z3));
      const float cc = fg * c_tm1[(size_t)r * UNITS + u] + ig * ct;
      const float hh = og * (1.f - 2.f / (__expf(2.f * cc) + 1.f));
      out[(size_t)r * UNITS + u] = hh;
      out[(size_t)BATCH * UNITS + (size_t)r * UNITS + u] = cc;
    }
}

// ---------------------------------------------------------------------------
// Fallback (only if d_ws too small): naive fp32, correct but slow.
// ---------------------------------------------------------------------------
__global__ __launch_bounds__(256) void lstm_naive(
    const float* __restrict__ x, const float* __restrict__ h,
    const float* __restrict__ c_tm1, const float* __restrict__ W,
    float* __restrict__ out) {
  int idx = blockIdx.x * 256 + threadIdx.x;
  int r = idx / UNITS;
  int u = idx % UNITS;
  float z[4] = {0.f, 0.f, 0.f, 0.f};
  for (int k = 0; k < KTOT; ++k) {
    float a = (k < UNITS) ? h[(size_t)r * UNITS + k] : x[(size_t)r * IDIM + k - UNITS];
#pragma unroll
    for (int g = 0; g < 4; ++g)
      z[g] += a * W[(size_t)k * NGATE + g * UNITS + u];
  }
  float ig = 1.f / (1.f + __expf(-z[0]));
  float fg = 1.f / (1.f + __expf(-z[1]));
  float ct = 1.f - 2.f / (__expf(2.f * z[2]) + 1.f);
  float og = 1.f / (1.f + __expf(-z[3]));
  float cc = fg * c_tm1[(size_t)r * UNITS + u] + ig * ct;
  float hh = og * (1.f - 2.f / (__expf(2.f * cc) + 1.f));
  out[(size_t)r * UNITS + u] = hh;
  out[(size_t)BATCH * UNITS + (size_t)r * UNITS + u] = cc;
}

extern "C" void kernel_launch(void* const* d_in, const int* in_sizes, int n_in,
                              void* d_out, int out_size, void* d_ws, size_t ws_size,
                              hipStream_t stream) {
  const float* x = (const float*)d_in[0];   // [2048][512]
  const float* h = (const float*)d_in[1];   // [2048][1024]
  const float* c = (const float*)d_in[2];   // [2048][1024]
  const float* W = (const float*)d_in[3];   // [1536][4096]
  float* out = (float*)d_out;               // h then c, 2 x [2048][1024]

  const size_t needA  = (size_t)BATCH * KTOT * sizeof(__hip_bfloat16);  // 6.29 MB
  const size_t needWt = (size_t)NGATE * KTOT * sizeof(__hip_bfloat16);  // 12.58 MB
  if (ws_size < needA + needWt) {
    hipLaunchKernelGGL(lstm_naive, dim3((BATCH * UNITS) / 256), dim3(256), 0, stream,
                       x, h, c, W, out);
    return;
  }

  bf16x8* A2  = (bf16x8*)d_ws;
  bf16x8* Wt2 = (bf16x8*)((char*)d_ws + needA);

  hipLaunchKernelGGL(prep, dim3(NBLK_A + NBLK_T), dim3(256), 0, stream, x, h, W, A2, Wt2);
  hipLaunchKernelGGL(lstm_gemm, dim3(512), dim3(256), 0, stream, A2, Wt2, c, out);
}